// Round 3
// baseline (77.675 us; speedup 1.0000x reference)
//
#include <hip/hip_runtime.h>
#include <hip/hip_fp16.h>

#define NPROJ  256
#define NDET   384
#define NS     256
#define TW     258                 // texture is 258x258 cells (uy,ux in [0,258))
#define TN     (TW * TW)           // 66564 entries = 4 * 129 * 129 (16 B each)
#define NRAY   (NPROJ * NDET)      // rays per batch
#define TPB    256

typedef _Float16 hvec2 __attribute__((ext_vector_type(2)));

// vertical-pair value: VP(uy,ux) = half2{ P(uy,ux), P(uy+1,ux) },
// P(py,px) = img[py-1][px-1], zero outside (verified R10-R15 builder).
__device__ __forceinline__ uint vp_pack(const float* im, int uy, int ux) {
    int x = ux - 1;
    if ((unsigned)x >= 256u) return 0u;
    float v0 = ((unsigned)(uy - 1) < 256u) ? im[((uy - 1) << 8) + x] : 0.0f;
    float v1 = ((unsigned)uy       < 256u) ? im[(uy << 8) + x]       : 0.0f;
    __half2 h2 = __floats2half2_rn(v0, v1);
    return *reinterpret_cast<uint*>(&h2);
}

// R18: 2x2-TILED batch-paired quad texture. Entry index for cell (uy,ux):
//   ai = ((uy>>1)*129 + (ux>>1))*4 + (uy&1)*2 + (ux&1)
// so each 64B cache line holds one 2x2 cell tile (orientation-isotropic
// footprint -> fewer distinct lines per wave-gather for diagonal angles).
// Entry payload unchanged (verified R15): uint4{ b0 VP(uy,ux), b0 VP(uy,ux+1),
//                                               b1 VP(uy,ux), b1 VP(uy,ux+1) }.
__global__ void quad_build(const float* __restrict__ src, uint4* __restrict__ dst) {
    int e = blockIdx.x * blockDim.x + threadIdx.x;     // over TN, in TILE order
    if (e >= TN) return;
    int tile = e >> 2;
    int off  = e & 3;
    int ty = tile / 129;
    int tx = tile - ty * 129;
    int uy = (ty << 1) | (off >> 1);
    int ux = (tx << 1) | (off & 1);
    const float* im0 = src;
    const float* im1 = src + (1 << 16);
    uint4 q;
    q.x = vp_pack(im0, uy, ux);
    q.y = vp_pack(im0, uy, ux + 1);
    q.z = vp_pack(im1, uy, ux);
    q.w = vp_pack(im1, uy, ux + 1);
    dst[e] = q;                                        // coalesced (e is dst index)
}

// Footprint-compacted (8 det x 8 slots, R14) + batch-paired (R15) + 4-deep
// MLP (R17) + R18: 2x2-tiled texture addressing. Loop structure identical to
// R17; only the cell->index mapping changed (int tile math, per-axis clamps).
__global__ __launch_bounds__(TPB) void fanproj_kernel(const uint4* __restrict__ T,
                                                      float* __restrict__ out) {
    int tid   = threadIdx.x;
    int lane  = tid & 63;
    int wv    = tid >> 6;
    int wrp0  = (blockIdx.x << 5) + (wv << 3);         // 32 ray-pairs/block
    int slot  = lane >> 3;                             // 0..7 sample phase
    int rp    = wrp0 + (lane & 7);                     // p*D + d  (pair id)

    int d = rp % NDET;
    int p = rp / NDET;                                 // in [0, NPROJ)

    const float dt = 1.4142135623730951f;              // diag / NS = sqrt(2)
    const float t0 = 219.68777079743137f;              // SID - diag/2 + 0.5*dt

    float theta = (float)p * (6.283185307179586f / (float)NPROJ);
    float st, ct;
    __sincosf(theta, &st, &ct);

    float srcx = -400.0f * ct;
    float srcy = -400.0f * st;
    float off  = ((float)d - 191.5f) * 1.2f;
    float rx   = fmaf(800.0f, ct, -off * st);
    float ry   = fmaf(800.0f, st,  off * ct);
    float n2   = rx * rx + ry * ry;
    float rn   = rsqrtf(n2);
    rn = rn * (1.5f - 0.5f * n2 * rn * rn);            // one Newton step
    rx *= rn;
    ry *= rn;

    // texture coords: X(s)=bxu+s*sx, Y(s)=byu+s*sy, footprint valid in [0,257)
    float bxu = fmaf(t0, rx, srcx) + 128.5f;
    float byu = fmaf(t0, ry, srcy) + 128.5f;
    float sx  = dt * rx;
    float sy  = dt * ry;

    // guard-free interval, EPS-shrunk (verified R8-R15); same for both batches
    const float EPS = 2e-3f;
    float sxs = (fabsf(sx) < 1e-9f) ? copysignf(1e-9f, sx) : sx;
    float sys = (fabsf(sy) < 1e-9f) ? copysignf(1e-9f, sy) : sy;
    float isx = 1.0f / sxs;
    float isy = 1.0f / sys;
    float ax0 = (0.0f - bxu) * isx, ax1 = (257.0f - bxu) * isx;
    float ay0 = (0.0f - byu) * isy, ay1 = (257.0f - byu) * isy;
    float lof = fmaxf(fminf(ax0, ax1), fminf(ay0, ay1)) + EPS;
    float hif = fminf(fmaxf(ax0, ax1), fmaxf(ay0, ay1)) - EPS;
    lof = fminf(fmaxf(lof, -1.0f), 300.0f);
    hif = fminf(fmaxf(hif, -1.0f), 300.0f);
    int slo = max(0,      (int)ceilf(lof));
    int shi = min(NS - 1, (int)floorf(hif));

    int s0  = slo + slot;
    int rem = shi - s0;                                // >=0: chain-0 valid
    float sf = (float)s0;

    float a00 = 0.0f, a01 = 0.0f;                      // chain 0 (s)
    float a10 = 0.0f, a11 = 0.0f;                      // chain 1 (s+8)
    float a20 = 0.0f, a21 = 0.0f;                      // chain 2 (s+16)
    float a30 = 0.0f, a31 = 0.0f;                      // chain 3 (s+24)

    // cell (clamped) -> 2x2-tiled entry index; safe for garbage coords
    auto mkidx = [](float xf, float yf) -> int {
        float xc = fminf(fmaxf(xf, 0.0f), 257.0f);
        float yc = fminf(fmaxf(yf, 0.0f), 257.0f);
        int xi = (int)xc;
        int yi = (int)yc;
        return (((yi >> 1) * 129 + (xi >> 1)) << 2) + ((yi & 1) << 1) + (xi & 1);
    };

    while (rem >= 0) {
        // ---- phase 1: addresses + weights for all 4 chains, issue loads ----
        float X0 = fmaf(sf,         sx, bxu), Y0 = fmaf(sf,         sy, byu);
        float X1 = fmaf(sf +  8.0f, sx, bxu), Y1 = fmaf(sf +  8.0f, sy, byu);
        float X2 = fmaf(sf + 16.0f, sx, bxu), Y2 = fmaf(sf + 16.0f, sy, byu);
        float X3 = fmaf(sf + 24.0f, sx, bxu), Y3 = fmaf(sf + 24.0f, sy, byu);
        sf += 32.0f;

        float xf0 = floorf(X0), yf0 = floorf(Y0);
        float xf1 = floorf(X1), yf1 = floorf(Y1);
        float xf2 = floorf(X2), yf2 = floorf(Y2);
        float xf3 = floorf(X3), yf3 = floorf(Y3);
        float wx0 = X0 - xf0, wy0 = Y0 - yf0;
        float wx1 = X1 - xf1, wy1 = Y1 - yf1;
        float wx2 = X2 - xf2, wy2 = Y2 - yf2;
        float wx3 = X3 - xf3, wy3 = Y3 - yf3;

        int ai0 = mkidx(xf0, yf0);
        int ai1 = mkidx(xf1, yf1);
        int ai2 = mkidx(xf2, yf2);
        int ai3 = mkidx(xf3, yf3);

        bool v1 = (rem >= 8), v2 = (rem >= 16), v3 = (rem >= 24);

        uint4 q0 = T[ai0];                             // chain 0 always valid
        uint4 q1 = {0u, 0u, 0u, 0u};
        uint4 q2 = {0u, 0u, 0u, 0u};
        uint4 q3 = {0u, 0u, 0u, 0u};
        if (v1) q1 = T[ai1];                           // exec-masked: no tail lines
        if (v2) q2 = T[ai2];
        if (v3) q3 = T[ai3];

        rem -= 32;

        // ---- phase 2: consume (weights zeroed for invalid chains) ----
        hvec2 hw0 = __builtin_bit_cast(hvec2,
                        __builtin_amdgcn_cvt_pkrtz(1.0f - wy0, wy0));
        float c00 = __builtin_amdgcn_fdot2(__builtin_bit_cast(hvec2, q0.x), hw0, 0.0f, false);
        float c01 = __builtin_amdgcn_fdot2(__builtin_bit_cast(hvec2, q0.y), hw0, 0.0f, false);
        a00 = fmaf(wx0, c01 - c00, a00 + c00);
        float c02 = __builtin_amdgcn_fdot2(__builtin_bit_cast(hvec2, q0.z), hw0, 0.0f, false);
        float c03 = __builtin_amdgcn_fdot2(__builtin_bit_cast(hvec2, q0.w), hw0, 0.0f, false);
        a01 = fmaf(wx0, c03 - c02, a01 + c02);

        uint hb1 = __builtin_bit_cast(uint,
                        __builtin_amdgcn_cvt_pkrtz(1.0f - wy1, wy1));
        hb1 = v1 ? hb1 : 0u;
        hvec2 hw1 = __builtin_bit_cast(hvec2, hb1);
        float c10 = __builtin_amdgcn_fdot2(__builtin_bit_cast(hvec2, q1.x), hw1, 0.0f, false);
        float c11 = __builtin_amdgcn_fdot2(__builtin_bit_cast(hvec2, q1.y), hw1, 0.0f, false);
        a10 = fmaf(wx1, c11 - c10, a10 + c10);
        float c12 = __builtin_amdgcn_fdot2(__builtin_bit_cast(hvec2, q1.z), hw1, 0.0f, false);
        float c13 = __builtin_amdgcn_fdot2(__builtin_bit_cast(hvec2, q1.w), hw1, 0.0f, false);
        a11 = fmaf(wx1, c13 - c12, a11 + c12);

        uint hb2 = __builtin_bit_cast(uint,
                        __builtin_amdgcn_cvt_pkrtz(1.0f - wy2, wy2));
        hb2 = v2 ? hb2 : 0u;
        hvec2 hw2 = __builtin_bit_cast(hvec2, hb2);
        float c20 = __builtin_amdgcn_fdot2(__builtin_bit_cast(hvec2, q2.x), hw2, 0.0f, false);
        float c21 = __builtin_amdgcn_fdot2(__builtin_bit_cast(hvec2, q2.y), hw2, 0.0f, false);
        a20 = fmaf(wx2, c21 - c20, a20 + c20);
        float c22 = __builtin_amdgcn_fdot2(__builtin_bit_cast(hvec2, q2.z), hw2, 0.0f, false);
        float c23 = __builtin_amdgcn_fdot2(__builtin_bit_cast(hvec2, q2.w), hw2, 0.0f, false);
        a21 = fmaf(wx2, c23 - c22, a21 + c22);

        uint hb3 = __builtin_bit_cast(uint,
                        __builtin_amdgcn_cvt_pkrtz(1.0f - wy3, wy3));
        hb3 = v3 ? hb3 : 0u;
        hvec2 hw3 = __builtin_bit_cast(hvec2, hb3);
        float c30 = __builtin_amdgcn_fdot2(__builtin_bit_cast(hvec2, q3.x), hw3, 0.0f, false);
        float c31 = __builtin_amdgcn_fdot2(__builtin_bit_cast(hvec2, q3.y), hw3, 0.0f, false);
        a30 = fmaf(wx3, c31 - c30, a30 + c30);
        float c32 = __builtin_amdgcn_fdot2(__builtin_bit_cast(hvec2, q3.z), hw3, 0.0f, false);
        float c33 = __builtin_amdgcn_fdot2(__builtin_bit_cast(hvec2, q3.w), hw3, 0.0f, false);
        a31 = fmaf(wx3, c33 - c32, a31 + c32);
    }

    float acc0 = (a00 + a10) + (a20 + a30);
    float acc1 = (a01 + a11) + (a21 + a31);

    // sum the 8 slot-partials (lanes sharing lane&7 differ in bits 3..5)
    acc0 += __shfl_xor(acc0, 8,  64);
    acc0 += __shfl_xor(acc0, 16, 64);
    acc0 += __shfl_xor(acc0, 32, 64);
    acc1 += __shfl_xor(acc1, 8,  64);
    acc1 += __shfl_xor(acc1, 16, 64);
    acc1 += __shfl_xor(acc1, 32, 64);
    if (slot == 0) {
        out[rp]        = acc0 * dt;                    // batch 0
        out[rp + NRAY] = acc1 * dt;                    // batch 1
    }
}

extern "C" void kernel_launch(void* const* d_in, const int* in_sizes, int n_in,
                              void* d_out, int out_size, void* d_ws, size_t ws_size,
                              hipStream_t stream) {
    const float* x = (const float*)d_in[0];
    float* out     = (float*)d_out;
    uint4* T       = (uint4*)d_ws;                     // TN*16 B = 1.07 MB

    quad_build<<<(TN + 255) / 256, 256, 0, stream>>>(x, T);

    // 3072 blocks x 256 threads: 32 ray-pairs/block x 3072 = 98304 pairs
    fanproj_kernel<<<3072, TPB, 0, stream>>>(T, out);
}

// Round 4
// 71.673 us; speedup vs baseline: 1.0837x; 1.0837x over previous
//
#include <hip/hip_runtime.h>
#include <hip/hip_fp16.h>

#define NPROJ  256
#define NDET   384
#define NS     256
#define TW     258                 // texture entries per row (uy,ux in [0,258))
#define TN     (TW * TW)           // 66564 entries (16 B each, both batches)
#define NRAY   (NPROJ * NDET)      // rays per batch
#define TPB    256

typedef _Float16 hvec2 __attribute__((ext_vector_type(2)));

// vertical-pair value: VP(uy,ux) = half2{ P(uy,ux), P(uy+1,ux) },
// P(py,px) = img[py-1][px-1], zero outside (verified R10-R15 builder).
__device__ __forceinline__ uint vp_pack(const float* im, int uy, int ux) {
    int x = ux - 1;
    if ((unsigned)x >= 256u) return 0u;
    float v0 = ((unsigned)(uy - 1) < 256u) ? im[((uy - 1) << 8) + x] : 0.0f;
    float v1 = ((unsigned)uy       < 256u) ? im[(uy << 8) + x]       : 0.0f;
    __half2 h2 = __floats2half2_rn(v0, v1);
    return *reinterpret_cast<uint*>(&h2);
}

// Batch-paired quad texture (verified R15): T[uy*TW+ux] = uint4{
//   b0 VP(uy,ux), b0 VP(uy,ux+1), b1 VP(uy,ux), b1 VP(uy,ux+1) }.
// Row-major: R18's 2x2 tiling regressed (+4.4us VALU, 0 line-count win).
__global__ void quad_build(const float* __restrict__ src, uint4* __restrict__ dst) {
    int e = blockIdx.x * blockDim.x + threadIdx.x;     // over TN
    if (e >= TN) return;
    int uy = e / TW;
    int ux = e - uy * TW;
    const float* im0 = src;
    const float* im1 = src + (1 << 16);
    uint4 q;
    q.x = vp_pack(im0, uy, ux);
    q.y = vp_pack(im0, uy, ux + 1);
    q.z = vp_pack(im1, uy, ux);
    q.w = vp_pack(im1, uy, ux + 1);
    dst[e] = q;
}

// Footprint-compacted (8 det x 8 slots, verified R14) + batch-paired (R15)
// + 2-deep MLP: each lane handles samples s and s+8 per iteration, two 16B
// gathers in flight. Sample B tail-masked by weight-zeroing (R13 technique).
// R16 (rotation), R17 (4-deep), R18 (2x2 tiling) all null-or-regressed:
// the gather is TA address-rate-bound (~55-64 cy/wave-gather), invariant
// to ILP and line layout. This is the best-measured structure (72.6 us).
__global__ __launch_bounds__(TPB) void fanproj_kernel(const uint4* __restrict__ T,
                                                      float* __restrict__ out) {
    int tid   = threadIdx.x;
    int lane  = tid & 63;
    int wv    = tid >> 6;
    int wrp0  = (blockIdx.x << 5) + (wv << 3);         // 32 ray-pairs/block
    int slot  = lane >> 3;                             // 0..7 sample phase
    int rp    = wrp0 + (lane & 7);                     // p*D + d  (pair id)

    int d = rp % NDET;
    int p = rp / NDET;                                 // in [0, NPROJ)

    const float dt = 1.4142135623730951f;              // diag / NS = sqrt(2)
    const float t0 = 219.68777079743137f;              // SID - diag/2 + 0.5*dt

    float theta = (float)p * (6.283185307179586f / (float)NPROJ);
    float st, ct;
    __sincosf(theta, &st, &ct);

    float srcx = -400.0f * ct;
    float srcy = -400.0f * st;
    float off  = ((float)d - 191.5f) * 1.2f;
    float rx   = fmaf(800.0f, ct, -off * st);
    float ry   = fmaf(800.0f, st,  off * ct);
    float n2   = rx * rx + ry * ry;
    float rn   = rsqrtf(n2);
    rn = rn * (1.5f - 0.5f * n2 * rn * rn);            // one Newton step
    rx *= rn;
    ry *= rn;

    // texture coords: X(s)=bxu+s*sx, Y(s)=byu+s*sy, footprint valid in [0,257)
    float bxu = fmaf(t0, rx, srcx) + 128.5f;
    float byu = fmaf(t0, ry, srcy) + 128.5f;
    float sx  = dt * rx;
    float sy  = dt * ry;

    // guard-free interval, EPS-shrunk (verified R8-R15); same for both batches
    const float EPS = 2e-3f;
    float sxs = (fabsf(sx) < 1e-9f) ? copysignf(1e-9f, sx) : sx;
    float sys = (fabsf(sy) < 1e-9f) ? copysignf(1e-9f, sy) : sy;
    float isx = 1.0f / sxs;
    float isy = 1.0f / sys;
    float ax0 = (0.0f - bxu) * isx, ax1 = (257.0f - bxu) * isx;
    float ay0 = (0.0f - byu) * isy, ay1 = (257.0f - byu) * isy;
    float lof = fmaxf(fminf(ax0, ax1), fminf(ay0, ay1)) + EPS;
    float hif = fminf(fmaxf(ax0, ax1), fmaxf(ay0, ay1)) - EPS;
    lof = fminf(fmaxf(lof, -1.0f), 300.0f);
    hif = fminf(fmaxf(hif, -1.0f), 300.0f);
    int slo = max(0,      (int)ceilf(lof));
    int shi = min(NS - 1, (int)floorf(hif));

    int s0  = slo + slot;
    int rem = shi - s0;                                // >=0: sample A valid
    float sf = (float)s0;
    float accA0 = 0.0f, accA1 = 0.0f;                  // chain A (s)
    float accB0 = 0.0f, accB1 = 0.0f;                  // chain B (s+8)

    while (rem >= 0) {
        float XA = fmaf(sf, sx, bxu);
        float YA = fmaf(sf, sy, byu);
        float sfB = sf + 8.0f;
        float XB = fmaf(sfB, sx, bxu);
        float YB = fmaf(sfB, sy, byu);
        sf += 16.0f;

        float xfA = floorf(XA), yfA = floorf(YA);
        float wxA = XA - xfA,  wyA = YA - yfA;
        float aFA = fmaf(yfA, 258.0f, xfA);
        aFA = fminf(fmaxf(aFA, 0.0f), 66563.0f);       // drift safety clamp
        int aiA = (int)aFA;

        float xfB = floorf(XB), yfB = floorf(YB);
        float wxB = XB - xfB,  wyB = YB - yfB;
        float aFB = fmaf(yfB, 258.0f, xfB);
        aFB = fminf(fmaxf(aFB, 0.0f), 66563.0f);       // clamp covers tail OOB
        int aiB = (int)aFB;

        uint4 qA = T[aiA];                             // 2 x 16B gathers in flight
        uint4 qB = T[aiB];

        // sample A: always valid inside the loop (rem >= 0)
        hvec2 hwA = __builtin_bit_cast(hvec2,
                        __builtin_amdgcn_cvt_pkrtz(1.0f - wyA, wyA));
        float a0 = __builtin_amdgcn_fdot2(__builtin_bit_cast(hvec2, qA.x),
                                          hwA, 0.0f, false);
        float a1 = __builtin_amdgcn_fdot2(__builtin_bit_cast(hvec2, qA.y),
                                          hwA, 0.0f, false);
        accA0 = fmaf(wxA, a1 - a0, accA0 + a0);
        float a2 = __builtin_amdgcn_fdot2(__builtin_bit_cast(hvec2, qA.z),
                                          hwA, 0.0f, false);
        float a3 = __builtin_amdgcn_fdot2(__builtin_bit_cast(hvec2, qA.w),
                                          hwA, 0.0f, false);
        accA1 = fmaf(wxA, a3 - a2, accA1 + a2);

        // sample B: tail-masked by zeroed weights (contributes exactly 0)
        uint hwBb = __builtin_bit_cast(uint,
                        __builtin_amdgcn_cvt_pkrtz(1.0f - wyB, wyB));
        hwBb = (rem >= 8) ? hwBb : 0u;
        hvec2 hwB = __builtin_bit_cast(hvec2, hwBb);
        float b0 = __builtin_amdgcn_fdot2(__builtin_bit_cast(hvec2, qB.x),
                                          hwB, 0.0f, false);
        float b1 = __builtin_amdgcn_fdot2(__builtin_bit_cast(hvec2, qB.y),
                                          hwB, 0.0f, false);
        accB0 = fmaf(wxB, b1 - b0, accB0 + b0);
        float b2 = __builtin_amdgcn_fdot2(__builtin_bit_cast(hvec2, qB.z),
                                          hwB, 0.0f, false);
        float b3 = __builtin_amdgcn_fdot2(__builtin_bit_cast(hvec2, qB.w),
                                          hwB, 0.0f, false);
        accB1 = fmaf(wxB, b3 - b2, accB1 + b2);

        rem -= 16;
    }

    float acc0 = accA0 + accB0;
    float acc1 = accA1 + accB1;

    // sum the 8 slot-partials (lanes sharing lane&7 differ in bits 3..5)
    acc0 += __shfl_xor(acc0, 8,  64);
    acc0 += __shfl_xor(acc0, 16, 64);
    acc0 += __shfl_xor(acc0, 32, 64);
    acc1 += __shfl_xor(acc1, 8,  64);
    acc1 += __shfl_xor(acc1, 16, 64);
    acc1 += __shfl_xor(acc1, 32, 64);
    if (slot == 0) {
        out[rp]        = acc0 * dt;                    // batch 0
        out[rp + NRAY] = acc1 * dt;                    // batch 1
    }
}

extern "C" void kernel_launch(void* const* d_in, const int* in_sizes, int n_in,
                              void* d_out, int out_size, void* d_ws, size_t ws_size,
                              hipStream_t stream) {
    const float* x = (const float*)d_in[0];
    float* out     = (float*)d_out;
    uint4* T       = (uint4*)d_ws;                     // TN*16 B = 1.07 MB

    quad_build<<<(TN + 255) / 256, 256, 0, stream>>>(x, T);

    // 3072 blocks x 256 threads: 32 ray-pairs/block x 3072 = 98304 pairs
    fanproj_kernel<<<3072, TPB, 0, stream>>>(T, out);
}